// Round 5
// baseline (390.542 us; speedup 1.0000x reference)
//
#include <hip/hip_runtime.h>

// SSIM, 64 slices of 512x512, 11x11 uniform window (separable box), zero pad.
// R8: eliminate old-row re-loads entirely — keep the band's first 7 rows in a
// register ring. Evidence: R4/R6/R7 all pin at ~7-8 B/cyc/CU of vmem traffic
// (insensitive to 2x TLP, to removing 50 DS ops/step, to removing ~90 VALU/step)
// -> hard fabric/LLC supply cap; only fewer bytes helps. Old-row re-reads were
// 128 MB of pure fabric traffic (L2 lifetime ~13k cyc << 88k cyc reuse gap).
// With RB=8 the subtracted rows are the first 7 streamed rows: ring them in
// registers (7 x 16 = 112 VGPRs), fully unroll the 18-row stream so all ring
// indices are compile-time literals (no scratch). launch_bounds(256,2) gives a
// 256-VGPR budget (~200 needed, no spill — R5's (256,4) clamp-spill lesson).
//  - 8 cols/lane x 64 lanes = full row width per wave
//  - vertical running box sums in registers (5 quantities x 8 cols)
//  - horizontal 11-tap via DPP wave-shifts (R7), zero-fill = image pad
//  - 1/121 window scale folded into K1/K2 rational (R7)

constexpr int IMG   = 512;
constexpr int RB    = 8;                  // output rows per wave (band)
constexpr int BANDS = IMG / RB;           // 64
constexpr int WPB   = 4;                  // waves per block
constexpr int NBLK  = 64 * BANDS / WPB;   // 1024 blocks
constexpr float K1 = 1.4641f;             // 0.01^2 * 121^2
constexpr float K2 = 13.1769f;            // 0.03^2 * 121^2

// DPP whole-wave shifts. wave_shr:1 -> lane i reads lane i-1 (lane 0 zero);
// wave_shl:1 -> lane i reads lane i+1 (lane 63 zero).
__device__ __forceinline__ float shr1(float v) {
  return __int_as_float(__builtin_amdgcn_update_dpp(
      0, __float_as_int(v), 0x138, 0xF, 0xF, true));
}
__device__ __forceinline__ float shl1(float v) {
  return __int_as_float(__builtin_amdgcn_update_dpp(
      0, __float_as_int(v), 0x130, 0xF, 0xF, true));
}

template <bool ATOMIC>
__global__ __launch_bounds__(256, 2) void ssim_main(const float* __restrict__ x,
                                                    const float* __restrict__ y,
                                                    float* __restrict__ out_ws) {
  __shared__ float wsum[WPB];

  const int tid  = threadIdx.x;
  const int lane = tid & 63;
  const int wid  = tid >> 6;

  // XCD clustering: consecutive blockIdx round-robin the 8 XCDs; give each
  // XCD 8 contiguous slices, walk a slice's block-groups consecutively.
  const int bid  = blockIdx.x;
  const int xcd  = bid & 7;
  const int qq   = bid >> 3;                 // 0..127
  const int z    = xcd * 8 + (qq >> 4);      // slice 0..63
  const int band = (qq & 15) * WPB + wid;    // 0..63
  const int o0   = band * RB;                // first output row
  const int gs   = o0 - 5;                   // first streamed input row

  const float* xs = x + (size_t)z * IMG * IMG + lane * 8;
  const float* ys = y + (size_t)z * IMG * IMG + lane * 8;

  float sX[8] = {}, sY[8] = {}, sXX[8] = {}, sYY[8] = {}, sXY[8] = {};
  float ringx[7][8], ringy[7][8];   // rows gs..gs+6, literal-indexed only
  float t0x[8], t0y[8], t1x[8], t1y[8];
  float acc = 0.f;

  auto ldrow8 = [&](const float* p, bool valid, float (&d)[8]) {
    if (valid) {
      const float4 a = *(const float4*)p;
      const float4 b = *(const float4*)(p + 4);
      d[0] = a.x; d[1] = a.y; d[2] = a.z; d[3] = a.w;
      d[4] = b.x; d[5] = b.y; d[6] = b.z; d[7] = b.w;
    } else {
#pragma unroll
      for (int j = 0; j < 8; ++j) d[j] = 0.f;
    }
  };

  // load row gs+i (x and y) into the given banks; OOB rows -> zeros (= pad)
  auto LD = [&](int i, float (&dx)[8], float (&dy)[8]) {
    const int gr = gs + i;
    const bool v = (unsigned)gr < (unsigned)IMG;
    ldrow8(xs + (size_t)gr * IMG, v, dx);
    ldrow8(ys + (size_t)gr * IMG, v, dy);
  };

  // warmup accumulate: S += contributions of one row
  auto accum = [&](const float (&cx)[8], const float (&cy)[8]) {
#pragma unroll
    for (int j = 0; j < 8; ++j) {
      sX[j] += cx[j];
      sY[j] += cy[j];
      sXX[j] = fmaf(cx[j], cx[j], sXX[j]);
      sYY[j] = fmaf(cy[j], cy[j], sYY[j]);
      sXY[j] = fmaf(cx[j], cy[j], sXY[j]);
    }
  };

  // steady update: S += new row - ring row
  auto stepv = [&](const float (&cx)[8], const float (&cy)[8],
                   const float (&ox)[8], const float (&oy)[8]) {
#pragma unroll
    for (int j = 0; j < 8; ++j) {
      sX[j] += cx[j] - ox[j];
      sY[j] += cy[j] - oy[j];
      sXX[j] = fmaf(cx[j], cx[j], fmaf(-ox[j], ox[j], sXX[j]));
      sYY[j] = fmaf(cy[j], cy[j], fmaf(-oy[j], oy[j], sYY[j]));
      sXY[j] = fmaf(cx[j], cy[j], fmaf(-ox[j], oy[j], sXY[j]));
    }
  };

  // Horizontal 11-tap window sums for one quantity (R7, DPP halo).
  auto hwin = [&](const float (&S)[8], float (&B)[8]) {
    const float vm5  = shr1(S[3]);
    const float vm4  = shr1(S[4]);
    const float vm3  = shr1(S[5]);
    const float vm2  = shr1(S[6]);
    const float vm1  = shr1(S[7]);
    const float vp8  = shl1(S[0]);
    const float vp9  = shl1(S[1]);
    const float vp10 = shl1(S[2]);
    const float vp11 = shl1(S[3]);
    const float vp12 = shl1(S[4]);
    float s = (((vm5 + vm4) + (vm3 + vm2)) + ((vm1 + S[0]) + (S[1] + S[2]))) +
              ((S[3] + S[4]) + S[5]);
    B[0] = s;
    s += S[6]  - vm5;  B[1] = s;
    s += S[7]  - vm4;  B[2] = s;
    s += vp8   - vm3;  B[3] = s;
    s += vp9   - vm2;  B[4] = s;
    s += vp10  - vm1;  B[5] = s;
    s += vp11  - S[0]; B[6] = s;
    s += vp12  - S[1]; B[7] = s;
  };

  // produce one output row from current S
  auto outp = [&]() {
    float bX[8], bY[8], bXX[8], bYY[8], bXY[8];
    hwin(sX, bX); hwin(sY, bY); hwin(sXX, bXX); hwin(sYY, bYY); hwin(sXY, bXY);
    // SSIM with 1/121 folded: (N1*N2)/(D1*D2), 121^4 cancels.
#pragma unroll
    for (int j = 0; j < 8; ++j) {
      const float bx  = bX[j];
      const float by  = bY[j];
      const float bxy = bx * by;
      const float sq  = fmaf(bx, bx, by * by);
      const float n1  = fmaf(2.f, bxy, K1);
      const float n2  = fmaf(242.f, bXY[j], fmaf(-2.f, bxy, K2));
      const float d1  = sq + K1;
      const float d2  = fmaf(121.f, bXX[j] + bYY[j], K2 - sq);
      acc += (n1 * n2) * __builtin_amdgcn_rcpf(d1 * d2);
    }
  };

  // ---- fully unrolled 18-row stream (all ring/bank indices literal) ----
  // warmup: accumulate rows 0..10; rows 0..6 retained in the ring.
  LD(0, ringx[0], ringy[0]);
  LD(1, ringx[1], ringy[1]);
  accum(ringx[0], ringy[0]);
  LD(2, ringx[2], ringy[2]);
  accum(ringx[1], ringy[1]);
  LD(3, ringx[3], ringy[3]);
  accum(ringx[2], ringy[2]);
  LD(4, ringx[4], ringy[4]);
  accum(ringx[3], ringy[3]);
  LD(5, ringx[5], ringy[5]);
  accum(ringx[4], ringy[4]);
  LD(6, ringx[6], ringy[6]);
  accum(ringx[5], ringy[5]);
  LD(7, t0x, t0y);
  accum(ringx[6], ringy[6]);
  LD(8, t1x, t1y);
  accum(t0x, t0y);                    // row 7
  LD(9, t0x, t0y);
  accum(t1x, t1y);                    // row 8
  LD(10, t1x, t1y);
  accum(t0x, t0y);                    // row 9
  LD(11, t0x, t0y);
  accum(t1x, t1y);                    // row 10 -> S = rows 0..10
  outp();                             // output row o0+0
  // steady: output t uses new row 10+t, subtracts ring row t-1
  LD(12, t1x, t1y);
  stepv(t0x, t0y, ringx[0], ringy[0]); outp();   // t=1 (row 11)
  LD(13, t0x, t0y);
  stepv(t1x, t1y, ringx[1], ringy[1]); outp();   // t=2 (row 12)
  LD(14, t1x, t1y);
  stepv(t0x, t0y, ringx[2], ringy[2]); outp();   // t=3 (row 13)
  LD(15, t0x, t0y);
  stepv(t1x, t1y, ringx[3], ringy[3]); outp();   // t=4 (row 14)
  LD(16, t1x, t1y);
  stepv(t0x, t0y, ringx[4], ringy[4]); outp();   // t=5 (row 15)
  LD(17, t0x, t0y);
  stepv(t1x, t1y, ringx[5], ringy[5]); outp();   // t=6 (row 16)
  stepv(t0x, t0y, ringx[6], ringy[6]); outp();   // t=7 (row 17)

  // ---- reduction: wave -> block -> global ----
#pragma unroll
  for (int off = 32; off > 0; off >>= 1) acc += __shfl_down(acc, off, 64);
  if (lane == 0) wsum[wid] = acc;
  __syncthreads();
  if (tid == 0) {
    const float t = wsum[0] + wsum[1] + wsum[2] + wsum[3];
    if (ATOMIC) {
      atomicAdd(out_ws, t);
    } else {
      out_ws[bid] = t;
    }
  }
}

__global__ void ssim_finalize(const float* __restrict__ partials, int n,
                              float* __restrict__ out) {
  __shared__ float wsum[4];
  float acc = 0.f;
  for (int i = threadIdx.x; i < n; i += 256) acc += partials[i];
#pragma unroll
  for (int off = 32; off > 0; off >>= 1) acc += __shfl_down(acc, off, 64);
  if ((threadIdx.x & 63) == 0) wsum[threadIdx.x >> 6] = acc;
  __syncthreads();
  if (threadIdx.x == 0) {
    const float t = wsum[0] + wsum[1] + wsum[2] + wsum[3];
    out[0] = 1.0f - t * (1.0f / (64.0f * 512.0f * 512.0f));
  }
}

__global__ void ssim_zero(float* p) {
  if (threadIdx.x == 0) p[0] = 0.f;
}

__global__ void ssim_finalize_atomic(const float* __restrict__ accp,
                                     float* __restrict__ out) {
  if (threadIdx.x == 0)
    out[0] = 1.0f - accp[0] * (1.0f / (64.0f * 512.0f * 512.0f));
}

extern "C" void kernel_launch(void* const* d_in, const int* in_sizes, int n_in,
                              void* d_out, int out_size, void* d_ws, size_t ws_size,
                              hipStream_t stream) {
  const float* x = (const float*)d_in[0];
  const float* y = (const float*)d_in[1];
  // d_in[2]: uniform 1/121 window, folded into K1/K2.
  float* out = (float*)d_out;

  dim3 grid(NBLK);      // 1024 blocks x 256 threads = 4096 waves = 64x64 bands
  dim3 block(256);

  if (ws_size >= (size_t)NBLK * sizeof(float)) {
    float* partials = (float*)d_ws;
    ssim_main<false><<<grid, block, 0, stream>>>(x, y, partials);
    ssim_finalize<<<1, 256, 0, stream>>>(partials, NBLK, out);
  } else {
    float* accp = (float*)d_ws;
    ssim_zero<<<1, 64, 0, stream>>>(accp);
    ssim_main<true><<<grid, block, 0, stream>>>(x, y, accp);
    ssim_finalize_atomic<<<1, 64, 0, stream>>>(accp, out);
  }
}

// Round 6
// 172.044 us; speedup vs baseline: 2.2700x; 2.2700x over previous
//
#include <hip/hip_runtime.h>

// SSIM, 64 slices of 512x512, 11x11 uniform window (separable box), zero pad.
// R9: make the software pipeline REAL. Evidence: R4/R6/R7 all show ~7000-cyc
// per-wave step latency vs ~250 VALU cyc and <=900-cyc physical memory latency
// -> the A/B-bank prefetch was being defeated: `if (valid)` branches around
// loads let the compiler sink loads to their use / go conservative on vmcnt
// (drain per step). Fix:
//  (1) branchless loads: clamp row to [0,511], ALWAYS load; per-bank float
//      mask applied at consume time (cxm = cx*m; sXX += cx*cxm -> OOB rows
//      contribute exactly 0, no NaN).
//  (2) sched_barrier(0) between prefetch-issue and compute pins issue order,
//      so loads for step i+1 fly during compute of step i (counted vmcnt).
// Geometry back to R4's best: RB=16 (26 streamed rows / 16 outputs, lowest
// FETCH per output), 2048 waves. DPP halo (R7), K-folded rational (R7).

constexpr int IMG   = 512;
constexpr int RB    = 16;                 // output rows per wave (band)
constexpr int BANDS = IMG / RB;           // 32
constexpr int WPB   = 4;                  // waves per block
constexpr int NBLK  = 64 * BANDS / WPB;   // 512 blocks
constexpr float K1 = 1.4641f;             // 0.01^2 * 121^2
constexpr float K2 = 13.1769f;            // 0.03^2 * 121^2

// DPP whole-wave shifts. wave_shr:1 -> lane i reads lane i-1 (lane 0 zero);
// wave_shl:1 -> lane i reads lane i+1 (lane 63 zero). Zero-fill == image pad.
__device__ __forceinline__ float shr1(float v) {
  return __int_as_float(__builtin_amdgcn_update_dpp(
      0, __float_as_int(v), 0x138, 0xF, 0xF, true));
}
__device__ __forceinline__ float shl1(float v) {
  return __int_as_float(__builtin_amdgcn_update_dpp(
      0, __float_as_int(v), 0x130, 0xF, 0xF, true));
}

template <bool ATOMIC>
__global__ __launch_bounds__(256, 2) void ssim_main(const float* __restrict__ x,
                                                    const float* __restrict__ y,
                                                    float* __restrict__ out_ws) {
  __shared__ float wsum[WPB];

  const int tid  = threadIdx.x;
  const int lane = tid & 63;
  const int wid  = tid >> 6;

  // XCD clustering: consecutive blockIdx round-robin the 8 XCDs; give each
  // XCD 8 contiguous slices, walk a slice's block-groups consecutively.
  const int bid  = blockIdx.x;
  const int xcd  = bid & 7;
  const int qq   = bid >> 3;                 // 0..63
  const int z    = xcd * 8 + (qq >> 3);      // slice 0..63
  const int band = (qq & 7) * WPB + wid;     // 0..31
  const int o0   = band * RB;                // first output row
  const int gs   = o0 - 5;                   // first streamed input row

  const float* xs = x + (size_t)z * IMG * IMG + lane * 8;
  const float* ys = y + (size_t)z * IMG * IMG + lane * 8;

  float sX[8] = {}, sY[8] = {}, sXX[8] = {}, sYY[8] = {}, sXY[8] = {};
  float cxA[8], cyA[8], oxA[8], oyA[8];
  float cxB[8], cyB[8], oxB[8], oyB[8];
  float mcA = 0.f, mcB = 0.f, moA = 1.f, moB = 1.f;
  float acc = 0.f;

  // Branchless row load: clamp row index (always in-bounds), return validity
  // mask as float. The mask is applied at CONSUME time, so no data dependency
  // is created here and the loads can stay in flight across the whole step.
  auto LDraw = [&](int gr, float (&dx)[8], float (&dy)[8]) -> float {
    const int grc = gr < 0 ? 0 : (gr > IMG - 1 ? IMG - 1 : gr);
    const float* px = xs + (size_t)grc * IMG;
    const float* py = ys + (size_t)grc * IMG;
    const float4 a = *(const float4*)px;
    const float4 b = *(const float4*)(px + 4);
    const float4 c = *(const float4*)py;
    const float4 d = *(const float4*)(py + 4);
    dx[0] = a.x; dx[1] = a.y; dx[2] = a.z; dx[3] = a.w;
    dx[4] = b.x; dx[5] = b.y; dx[6] = b.z; dx[7] = b.w;
    dy[0] = c.x; dy[1] = c.y; dy[2] = c.z; dy[3] = c.w;
    dy[4] = d.x; dy[5] = d.y; dy[6] = d.z; dy[7] = d.w;
    return ((unsigned)gr < (unsigned)IMG) ? 1.f : 0.f;
  };

  // warmup consume: S += masked contributions of one row
  auto consumeW = [&](const float (&cx)[8], const float (&cy)[8], float mc) {
#pragma unroll
    for (int j = 0; j < 8; ++j) {
      const float cxm = cx[j] * mc, cym = cy[j] * mc;
      sX[j] += cxm;
      sY[j] += cym;
      sXX[j] = fmaf(cx[j], cxm, sXX[j]);
      sYY[j] = fmaf(cy[j], cym, sYY[j]);
      sXY[j] = fmaf(cx[j], cym, sXY[j]);
    }
  };

  // steady consume: S += masked new row - masked old row
  auto consumeS = [&](const float (&cx)[8], const float (&cy)[8], float mc,
                      const float (&ox)[8], const float (&oy)[8], float mo) {
#pragma unroll
    for (int j = 0; j < 8; ++j) {
      const float cxm = cx[j] * mc, cym = cy[j] * mc;
      const float oxm = ox[j] * mo, oym = oy[j] * mo;
      sX[j] += cxm - oxm;
      sY[j] += cym - oym;
      sXX[j] = fmaf(cx[j], cxm, fmaf(-ox[j], oxm, sXX[j]));
      sYY[j] = fmaf(cy[j], cym, fmaf(-oy[j], oym, sYY[j]));
      sXY[j] = fmaf(cx[j], cym, fmaf(-ox[j], oym, sXY[j]));
    }
  };

  // Horizontal 11-tap window sums for one quantity (DPP halo).
  auto hwin = [&](const float (&S)[8], float (&B)[8]) {
    const float vm5  = shr1(S[3]);
    const float vm4  = shr1(S[4]);
    const float vm3  = shr1(S[5]);
    const float vm2  = shr1(S[6]);
    const float vm1  = shr1(S[7]);
    const float vp8  = shl1(S[0]);
    const float vp9  = shl1(S[1]);
    const float vp10 = shl1(S[2]);
    const float vp11 = shl1(S[3]);
    const float vp12 = shl1(S[4]);
    float s = (((vm5 + vm4) + (vm3 + vm2)) + ((vm1 + S[0]) + (S[1] + S[2]))) +
              ((S[3] + S[4]) + S[5]);
    B[0] = s;
    s += S[6]  - vm5;  B[1] = s;
    s += S[7]  - vm4;  B[2] = s;
    s += vp8   - vm3;  B[3] = s;
    s += vp9   - vm2;  B[4] = s;
    s += vp10  - vm1;  B[5] = s;
    s += vp11  - S[0]; B[6] = s;
    s += vp12  - S[1]; B[7] = s;
  };

  // produce one output row from current S
  auto outp = [&]() {
    float bX[8], bY[8], bXX[8], bYY[8], bXY[8];
    hwin(sX, bX); hwin(sY, bY); hwin(sXX, bXX); hwin(sYY, bYY); hwin(sXY, bXY);
    // SSIM with 1/121 folded: (N1*N2)/(D1*D2), 121^4 cancels.
#pragma unroll
    for (int j = 0; j < 8; ++j) {
      const float bx  = bX[j];
      const float by  = bY[j];
      const float bxy = bx * by;
      const float sq  = fmaf(bx, bx, by * by);
      const float n1  = fmaf(2.f, bxy, K1);
      const float n2  = fmaf(242.f, bXY[j], fmaf(-2.f, bxy, K2));
      const float d1  = sq + K1;
      const float d2  = fmaf(121.f, bXX[j] + bYY[j], K2 - sq);
      acc += (n1 * n2) * __builtin_amdgcn_rcpf(d1 * d2);
    }
  };

  // Prologue: row gs into bank A; zero the old banks (masks make them inert,
  // but uninitialized registers could be NaN and NaN*0 = NaN).
  mcA = LDraw(gs, cxA, cyA);
#pragma unroll
  for (int j = 0; j < 8; ++j) {
    oxA[j] = 0.f; oyA[j] = 0.f; oxB[j] = 0.f; oyB[j] = 0.f;
  }

  // warmup: steps 0..9 (consume row i, prefetch row i+1; no outputs)
#pragma unroll 1
  for (int i = 0; i < 10; i += 2) {
    mcB = LDraw(gs + i + 1, cxB, cyB);
    __builtin_amdgcn_sched_barrier(0);
    consumeW(cxA, cyA, mcA);
    mcA = LDraw(gs + i + 2, cxA, cyA);
    __builtin_amdgcn_sched_barrier(0);
    consumeW(cxB, cyB, mcB);
  }

  // steady: steps 10..RB+9. Step i adds row gs+i, subtracts row gs+i-11
  // (o-bank loaded during step i-1), outputs row o0+i-10.
#pragma unroll 1
  for (int i = 10; i < RB + 10; i += 2) {
    mcB = LDraw(gs + i + 1, cxB, cyB);
    moB = LDraw(gs + i - 10, oxB, oyB);
    __builtin_amdgcn_sched_barrier(0);
    consumeS(cxA, cyA, mcA, oxA, oyA, moA);
    outp();
    mcA = LDraw(gs + i + 2, cxA, cyA);
    moA = LDraw(gs + i - 9, oxA, oyA);
    __builtin_amdgcn_sched_barrier(0);
    consumeS(cxB, cyB, mcB, oxB, oyB, moB);
    outp();
  }

  // ---- reduction: wave -> block -> global ----
#pragma unroll
  for (int off = 32; off > 0; off >>= 1) acc += __shfl_down(acc, off, 64);
  if (lane == 0) wsum[wid] = acc;
  __syncthreads();
  if (tid == 0) {
    const float t = wsum[0] + wsum[1] + wsum[2] + wsum[3];
    if (ATOMIC) {
      atomicAdd(out_ws, t);
    } else {
      out_ws[bid] = t;
    }
  }
}

__global__ void ssim_finalize(const float* __restrict__ partials, int n,
                              float* __restrict__ out) {
  __shared__ float wsum[4];
  float acc = 0.f;
  for (int i = threadIdx.x; i < n; i += 256) acc += partials[i];
#pragma unroll
  for (int off = 32; off > 0; off >>= 1) acc += __shfl_down(acc, off, 64);
  if ((threadIdx.x & 63) == 0) wsum[threadIdx.x >> 6] = acc;
  __syncthreads();
  if (threadIdx.x == 0) {
    const float t = wsum[0] + wsum[1] + wsum[2] + wsum[3];
    out[0] = 1.0f - t * (1.0f / (64.0f * 512.0f * 512.0f));
  }
}

__global__ void ssim_zero(float* p) {
  if (threadIdx.x == 0) p[0] = 0.f;
}

__global__ void ssim_finalize_atomic(const float* __restrict__ accp,
                                     float* __restrict__ out) {
  if (threadIdx.x == 0)
    out[0] = 1.0f - accp[0] * (1.0f / (64.0f * 512.0f * 512.0f));
}

extern "C" void kernel_launch(void* const* d_in, const int* in_sizes, int n_in,
                              void* d_out, int out_size, void* d_ws, size_t ws_size,
                              hipStream_t stream) {
  const float* x = (const float*)d_in[0];
  const float* y = (const float*)d_in[1];
  // d_in[2]: uniform 1/121 window, folded into K1/K2.
  float* out = (float*)d_out;

  dim3 grid(NBLK);      // 512 blocks x 256 threads = 2048 waves = 64x32 bands
  dim3 block(256);

  if (ws_size >= (size_t)NBLK * sizeof(float)) {
    float* partials = (float*)d_ws;
    ssim_main<false><<<grid, block, 0, stream>>>(x, y, partials);
    ssim_finalize<<<1, 256, 0, stream>>>(partials, NBLK, out);
  } else {
    float* accp = (float*)d_ws;
    ssim_zero<<<1, 64, 0, stream>>>(accp);
    ssim_main<true><<<grid, block, 0, stream>>>(x, y, accp);
    ssim_finalize_atomic<<<1, 64, 0, stream>>>(accp, out);
  }
}